// Round 1
// baseline (174.208 us; speedup 1.0000x reference)
//
#include <hip/hip_runtime.h>
#include <hip/hip_bf16.h>

typedef short bf16x8 __attribute__((ext_vector_type(8)));
typedef float f32x4  __attribute__((ext_vector_type(4)));

#define NB 512
#define NN 256
#define ND 128
#define H_STRIDE 136    // s_h row stride (bf16 elems)
#define HT_STRIDE 264   // s_ht row stride
#define P_STRIDE 136    // per-wave P row stride
#define SMEM_SHORTS (NN*H_STRIDE + ND*HT_STRIDE + 4*16*P_STRIDE + 4*ND)
#define SMEM_BYTES (SMEM_SHORTS * 2)

__device__ __forceinline__ short f2b(float f) {
    union { float f; unsigned u; } v; v.f = f;
    unsigned r = v.u + 0x7fffu + ((v.u >> 16) & 1u);   // RNE fp32->bf16
    return (short)(r >> 16);
}
__device__ __forceinline__ float b2f(short s) {
    union { unsigned u; float f; } v; v.u = ((unsigned)(unsigned short)s) << 16;
    return v.f;
}
__device__ __forceinline__ void lds_fence() {
    asm volatile("s_waitcnt lgkmcnt(0)" ::: "memory");
    __builtin_amdgcn_sched_barrier(0);
}

__global__ __launch_bounds__(256, 1)
void gat_fused(const float* __restrict__ hidden, const int* __restrict__ adj,
               const float* __restrict__ a0, const float* __restrict__ a1,
               const float* __restrict__ a2, const float* __restrict__ a3,
               float* __restrict__ out)
{
    extern __shared__ short smem[];
    short* s_h  = smem;                      // [256][136] bf16, row-major h
    short* s_ht = s_h + NN * H_STRIDE;       // [128][264] bf16, transposed h
    short* s_p  = s_ht + ND * HT_STRIDE;     // [4][16][136] per-wave P buffer
    short* s_a  = s_p + 4 * 16 * P_STRIDE;   // [4][128] bf16 a_r

    const int b    = blockIdx.x;
    const int tid  = threadIdx.x;
    const int wave = tid >> 6;
    const int lane = tid & 63;
    const int c = lane & 15;   // fragment column / row index (l&15)
    const int g = lane >> 4;   // k-group (l>>4)

    // ---- stage h[b] -> s_h (bf16) and s_ht (bf16, transposed) ----
    const float* hb = hidden + (size_t)b * (NN * ND);
    for (int idx = tid * 4; idx < NN * ND; idx += 256 * 4) {
        const float4 v = *(const float4*)(hb + idx);
        const int j = idx >> 7, d = idx & (ND - 1);
        const short b0 = f2b(v.x), b1 = f2b(v.y), b2 = f2b(v.z), b3 = f2b(v.w);
        union { short s[4]; uint2 u; } pk;
        pk.s[0] = b0; pk.s[1] = b1; pk.s[2] = b2; pk.s[3] = b3;
        *(uint2*)&s_h[j * H_STRIDE + d] = pk.u;
        s_ht[(d + 0) * HT_STRIDE + j] = b0;
        s_ht[(d + 1) * HT_STRIDE + j] = b1;
        s_ht[(d + 2) * HT_STRIDE + j] = b2;
        s_ht[(d + 3) * HT_STRIDE + j] = b3;
    }
    if (tid < ND) {
        s_a[0 * ND + tid] = f2b(a0[tid]);
        s_a[1 * ND + tid] = f2b(a1[tid]);
        s_a[2 * ND + tid] = f2b(a2[tid]);
        s_a[3 * ND + tid] = f2b(a3[tid]);
    }
    __syncthreads();

    short* s_pw = s_p + wave * 16 * P_STRIDE;
    const int* adj_b = adj + ((size_t)b << 16);
    float* out_b = out + (size_t)b * (NN * ND);

    for (int n = 0; n < 4; ++n) {
        const int it = wave + 4 * n;
        const int ibase = it * 16;

        // ---- Q fragments for this i-tile, pre-scaled by each a_r ----
        bf16x8 qs[4][4];   // [relation][k-step]
        #pragma unroll
        for (int s = 0; s < 4; ++s) {
            const bf16x8 q = *(const bf16x8*)&s_h[(ibase + c) * H_STRIDE + s * 32 + g * 8];
            #pragma unroll
            for (int r = 0; r < 4; ++r) {
                const bf16x8 av = *(const bf16x8*)&s_a[r * ND + s * 32 + g * 8];
                bf16x8 o;
                #pragma unroll
                for (int e = 0; e < 8; ++e) o[e] = f2b(b2f(q[e]) * b2f(av[e]));
                qs[r][s] = o;
            }
        }

        // ---- scores: 16 j-tiles, 4 relations each, select by adj ----
        float sc[16][4];
        #pragma unroll
        for (int jt = 0; jt < 16; ++jt) {
            const int jbase = jt * 16;
            const int* ap = adj_b + (ibase + 4 * g) * NN + jbase + c;
            const int av0 = ap[0], av1 = ap[NN], av2 = ap[2 * NN], av3 = ap[3 * NN];
            f32x4 e0 = {0.f,0.f,0.f,0.f}, e1 = {0.f,0.f,0.f,0.f};
            f32x4 e2 = {0.f,0.f,0.f,0.f}, e3 = {0.f,0.f,0.f,0.f};
            #pragma unroll
            for (int s = 0; s < 4; ++s) {
                const bf16x8 bv = *(const bf16x8*)&s_h[(jbase + c) * H_STRIDE + s * 32 + g * 8];
                e0 = __builtin_amdgcn_mfma_f32_16x16x32_bf16(qs[0][s], bv, e0, 0, 0, 0);
                e1 = __builtin_amdgcn_mfma_f32_16x16x32_bf16(qs[1][s], bv, e1, 0, 0, 0);
                e2 = __builtin_amdgcn_mfma_f32_16x16x32_bf16(qs[2][s], bv, e2, 0, 0, 0);
                e3 = __builtin_amdgcn_mfma_f32_16x16x32_bf16(qs[3][s], bv, e3, 0, 0, 0);
            }
            #pragma unroll
            for (int q = 0; q < 4; ++q) {
                const int a = (q == 0) ? av0 : (q == 1) ? av1 : (q == 2) ? av2 : av3;
                float e = (a == 1) ? e0[q] : (a == 2) ? e1[q] : (a == 3) ? e2[q] : e3[q];
                e = e > 0.f ? e : 0.2f * e;                    // leakyrelu(0.2)
                sc[jt][q] = (a >= 1) ? e : -9.0e15f;           // adj==0 -> mask
            }
        }

        // ---- row softmax (rows live across the 16 lanes sharing g) ----
        float m[4] = {-3.0e38f, -3.0e38f, -3.0e38f, -3.0e38f};
        #pragma unroll
        for (int jt = 0; jt < 16; ++jt)
            #pragma unroll
            for (int q = 0; q < 4; ++q) m[q] = fmaxf(m[q], sc[jt][q]);
        #pragma unroll
        for (int off = 1; off < 16; off <<= 1) {
            #pragma unroll
            for (int q = 0; q < 4; ++q) m[q] = fmaxf(m[q], __shfl_xor(m[q], off, 64));
        }
        float sum[4] = {0.f, 0.f, 0.f, 0.f};
        #pragma unroll
        for (int jt = 0; jt < 16; ++jt)
            #pragma unroll
            for (int q = 0; q < 4; ++q) {
                const float p = __expf(sc[jt][q] - m[q]);
                sc[jt][q] = p;
                sum[q] += p;
            }
        #pragma unroll
        for (int off = 1; off < 16; off <<= 1) {
            #pragma unroll
            for (int q = 0; q < 4; ++q) sum[q] += __shfl_xor(sum[q], off, 64);
        }
        float rinv[4];
        #pragma unroll
        for (int q = 0; q < 4; ++q) rinv[q] = 1.f / sum[q];

        // ---- PV: out_tile[16 x 128] = P[16 x 256] * h[256 x 128] ----
        f32x4 oacc[8];
        #pragma unroll
        for (int dt = 0; dt < 8; ++dt) oacc[dt] = (f32x4){0.f,0.f,0.f,0.f};
        #pragma unroll
        for (int half = 0; half < 2; ++half) {
            lds_fence();   // WAR: prior reads of s_pw complete before overwrite
            #pragma unroll
            for (int jj = 0; jj < 8; ++jj) {
                #pragma unroll
                for (int q = 0; q < 4; ++q)
                    s_pw[(4 * g + q) * P_STRIDE + jj * 16 + c] = f2b(sc[half * 8 + jj][q]);
            }
            lds_fence();   // RAW: writes visible before fragment reads
            #pragma unroll
            for (int s = 0; s < 4; ++s) {
                const bf16x8 pa = *(const bf16x8*)&s_pw[c * P_STRIDE + s * 32 + g * 8];
                #pragma unroll
                for (int dt = 0; dt < 8; ++dt) {
                    const bf16x8 vb = *(const bf16x8*)
                        &s_ht[(dt * 16 + c) * HT_STRIDE + half * 128 + s * 32 + g * 8];
                    oacc[dt] = __builtin_amdgcn_mfma_f32_16x16x32_bf16(pa, vb, oacc[dt], 0, 0, 0);
                }
            }
        }

        // ---- epilogue: scale by 1/sum and store fp32 ----
        #pragma unroll
        for (int dt = 0; dt < 8; ++dt)
            #pragma unroll
            for (int q = 0; q < 4; ++q)
                out_b[(ibase + 4 * g + q) * ND + dt * 16 + c] = oacc[dt][q] * rinv[q];
    }
}

extern "C" void kernel_launch(void* const* d_in, const int* in_sizes, int n_in,
                              void* d_out, int out_size, void* d_ws, size_t ws_size,
                              hipStream_t stream) {
    const float* hidden = (const float*)d_in[0];
    const int*   adjp   = (const int*)d_in[1];
    const float* a0 = (const float*)d_in[2];
    const float* a1 = (const float*)d_in[3];
    const float* a2 = (const float*)d_in[4];
    const float* a3 = (const float*)d_in[5];
    float* outp = (float*)d_out;

    (void)hipFuncSetAttribute((const void*)gat_fused,
                              hipFuncAttributeMaxDynamicSharedMemorySize, SMEM_BYTES);
    gat_fused<<<dim3(NB), dim3(256), SMEM_BYTES, stream>>>(hidden, adjp, a0, a1, a2, a3, outp);
}